// Round 2
// baseline (1138.232 us; speedup 1.0000x reference)
//
#include <hip/hip_runtime.h>
#include <hip/hip_bf16.h>

typedef unsigned short u16;

#define M_DIM 16384
#define N_DIM 4096
#define K_DIM 4096
#define R_DIM 64

typedef __bf16 bf16x8 __attribute__((ext_vector_type(8)));
typedef float floatx4 __attribute__((ext_vector_type(4)));
typedef u16 u16x8 __attribute__((ext_vector_type(8)));

__device__ __forceinline__ u16 f2bf(float f) {
    union { float f; unsigned int i; } v;
    v.f = f;
    unsigned int r = v.i + 0x7fffu + ((v.i >> 16) & 1u);  // RNE
    return (u16)(r >> 16);
}

// ---------------------------------------------------------------------------
// Kernel 0: fp32 -> bf16 round-convert (x). Each thread: 8 floats -> 8 bf16.
// ---------------------------------------------------------------------------
__global__ __launch_bounds__(256) void cvt_bf16(const float* __restrict__ in,
                                                u16* __restrict__ out, int n8) {
    int i = blockIdx.x * 256 + threadIdx.x;
    if (i >= n8) return;
    const float4* p = (const float4*)in + (size_t)i * 2;
    float4 a = p[0], b = p[1];
    u16x8 r;
    r[0] = f2bf(a.x); r[1] = f2bf(a.y); r[2] = f2bf(a.z); r[3] = f2bf(a.w);
    r[4] = f2bf(b.x); r[5] = f2bf(b.y); r[6] = f2bf(b.z); r[7] = f2bf(b.w);
    *((u16x8*)out + i) = r;
}

// ---------------------------------------------------------------------------
// Kernel 1: fold LoRA into the weight (fp32 in, bf16 out).
// Wc[n][k] = bf16( W_res[n][k] + sum_r lora_B[n][r] * lora_A[r][k] )
// grid: (K/256, N/16), block 256. Each thread: 1 k, 16 n's.
// ---------------------------------------------------------------------------
__global__ __launch_bounds__(256) void prep_w(const float* __restrict__ W,
                                              const float* __restrict__ lA,
                                              const float* __restrict__ lB,
                                              u16* __restrict__ Wc) {
    __shared__ float Bs[16][R_DIM];
    const int k = blockIdx.x * 256 + threadIdx.x;
    const int n0 = blockIdx.y * 16;

    for (int i = threadIdx.x; i < 16 * R_DIM; i += 256) {
        int j = i >> 6, r = i & 63;
        Bs[j][r] = lB[(size_t)(n0 + j) * R_DIM + r];
    }
    __syncthreads();

    float acc[16];
#pragma unroll
    for (int j = 0; j < 16; ++j) acc[j] = 0.f;

    for (int r = 0; r < R_DIM; ++r) {
        float a = lA[(size_t)r * K_DIM + k];
#pragma unroll
        for (int j = 0; j < 16; ++j) acc[j] += Bs[j][r] * a;
    }

#pragma unroll
    for (int j = 0; j < 16; ++j) {
        size_t idx = (size_t)(n0 + j) * K_DIM + k;
        Wc[idx] = f2bf(W[idx] + acc[j]);
    }
}

// ---------------------------------------------------------------------------
// Kernel 2: C[M][N] = Ab[M][K](bf16) @ Wc[N][K](bf16)^T + bias(f32), C f32.
// m97 structure: 128x128 tile, BK=32, 4 waves, 4x4 of 16x16x32 MFMA each,
// staging via global_load_lds width=16 (wave-uniform base + lane*16).
// ---------------------------------------------------------------------------
__global__ __launch_bounds__(256) void gemm_bias(
    const u16* __restrict__ A,      // x bf16 [M][K]
    const u16* __restrict__ B,      // W_comb bf16 [N][K]
    const float* __restrict__ bias, // [N] f32
    float* __restrict__ C) {        // [M][N] f32
    __shared__ __align__(16) u16 As[128 * 32];
    __shared__ __align__(16) u16 Bs[128 * 32];

    const int tid  = threadIdx.x;
    const int lane = tid & 63;
    const int wave = tid >> 6;
    const int wm = wave >> 1;   // 0..1
    const int wn = wave & 1;    // 0..1
    const int m0 = blockIdx.y * 128;
    const int n0 = blockIdx.x * 128;

    // staging: thread t covers row t>>2 (and row 64 + t>>2), k-offset (t&3)*8
    const int srow  = tid >> 2;
    const int skoff = (tid & 3) * 8;
    const u16* gA0 = A + (size_t)(m0 + srow) * K_DIM + skoff;
    const u16* gA1 = A + (size_t)(m0 + 64 + srow) * K_DIM + skoff;
    const u16* gB0 = B + (size_t)(n0 + srow) * K_DIM + skoff;
    const u16* gB1 = B + (size_t)(n0 + 64 + srow) * K_DIM + skoff;
    u16* lA0 = As + tid * 8;          // byte offset tid*16 (wave base + lane*16)
    u16* lA1 = As + 2048 + tid * 8;   // rows 64..127
    u16* lB0 = Bs + tid * 8;
    u16* lB1 = Bs + 2048 + tid * 8;

    floatx4 acc[4][4];
#pragma unroll
    for (int mt = 0; mt < 4; ++mt)
#pragma unroll
        for (int nt = 0; nt < 4; ++nt)
            acc[mt][nt] = (floatx4){0.f, 0.f, 0.f, 0.f};

    // fragment addresses: m/n = lane&15 within tile, k = (lane>>4)*8
    const int frow = lane & 15;
    const int fk   = (lane >> 4) * 8;

    for (int k0 = 0; k0 < K_DIM; k0 += 32) {
        __builtin_amdgcn_global_load_lds(
            (const __attribute__((address_space(1))) void*)(gA0 + k0),
            (__attribute__((address_space(3))) void*)lA0, 16, 0, 0);
        __builtin_amdgcn_global_load_lds(
            (const __attribute__((address_space(1))) void*)(gA1 + k0),
            (__attribute__((address_space(3))) void*)lA1, 16, 0, 0);
        __builtin_amdgcn_global_load_lds(
            (const __attribute__((address_space(1))) void*)(gB0 + k0),
            (__attribute__((address_space(3))) void*)lB0, 16, 0, 0);
        __builtin_amdgcn_global_load_lds(
            (const __attribute__((address_space(1))) void*)(gB1 + k0),
            (__attribute__((address_space(3))) void*)lB1, 16, 0, 0);
        __syncthreads();

        bf16x8 af[4], bfr[4];
#pragma unroll
        for (int mt = 0; mt < 4; ++mt)
            af[mt] = *(const bf16x8*)&As[(wm * 64 + mt * 16 + frow) * 32 + fk];
#pragma unroll
        for (int nt = 0; nt < 4; ++nt)
            bfr[nt] = *(const bf16x8*)&Bs[(wn * 64 + nt * 16 + frow) * 32 + fk];

#pragma unroll
        for (int mt = 0; mt < 4; ++mt)
#pragma unroll
            for (int nt = 0; nt < 4; ++nt)
                acc[mt][nt] = __builtin_amdgcn_mfma_f32_16x16x32_bf16(
                    af[mt], bfr[nt], acc[mt][nt], 0, 0, 0);

        __syncthreads();
    }

    // epilogue: C/D layout col = lane&15, row = (lane>>4)*4 + r  [m89/m91]
    const int crow0 = m0 + wm * 64;
    const int ccol0 = n0 + wn * 64;
#pragma unroll
    for (int nt = 0; nt < 4; ++nt) {
        const int col = ccol0 + nt * 16 + (lane & 15);
        const float bv = bias[col];
#pragma unroll
        for (int mt = 0; mt < 4; ++mt) {
            const int row = crow0 + mt * 16 + (lane >> 4) * 4;
#pragma unroll
            for (int r = 0; r < 4; ++r)
                C[(size_t)(row + r) * N_DIM + col] = acc[mt][nt][r] + bv;
        }
    }
}

extern "C" void kernel_launch(void* const* d_in, const int* in_sizes, int n_in,
                              void* d_out, int out_size, void* d_ws, size_t ws_size,
                              hipStream_t stream) {
    const float* x    = (const float*)d_in[0];  // [M][K] f32
    const float* W    = (const float*)d_in[1];  // [N][K] f32
    const float* bias = (const float*)d_in[2];  // [N] f32
    const float* lA   = (const float*)d_in[3];  // [R][K] f32
    const float* lB   = (const float*)d_in[4];  // [N][R] f32
    float* out = (float*)d_out;                 // [M][N] f32

    // workspace layout: Wc bf16 [N*K] (32 MB), then x_bf16 [M*K] (128 MB)
    u16* Wc = (u16*)d_ws;
    u16* xb = Wc + (size_t)N_DIM * K_DIM;

    dim3 g0((M_DIM * (K_DIM / 8) + 255) / 256 / 1);
    cvt_bf16<<<dim3((M_DIM * K_DIM / 8 + 255) / 256), 256, 0, stream>>>(
        x, xb, M_DIM * K_DIM / 8);

    dim3 g1(K_DIM / 256, N_DIM / 16);
    prep_w<<<g1, 256, 0, stream>>>(W, lA, lB, Wc);

    dim3 g2(N_DIM / 128, M_DIM / 128);
    gemm_bias<<<g2, 256, 0, stream>>>(xb, Wc, bias, out);
}